// Round 1
// 1416.498 us; speedup vs baseline: 1.0476x; 1.0476x over previous
//
#include <hip/hip_runtime.h>
#include <hip/hip_bf16.h>
#include <stdint.h>

// ---------------- types ----------------
typedef __attribute__((ext_vector_type(4))) float f32x4;
typedef __attribute__((ext_vector_type(4))) unsigned int u32x4;
typedef __bf16 v8bf __attribute__((ext_vector_type(8)));

// async global->LDS, 16B per lane. LDS dest must be uniform + lane*16.
#define GLL16(gp, lp) __builtin_amdgcn_global_load_lds( \
    (const __attribute__((address_space(1))) unsigned int*)(const void*)(gp), \
    (__attribute__((address_space(3))) unsigned int*)(void*)(lp), 16, 0, 0)

// pack two f32 -> two bf16 (truncate): short0=bf16(a) (lower k), short1=bf16(b)
__device__ __forceinline__ unsigned pkbf(float a, float b) {
  return __builtin_amdgcn_perm(__float_as_uint(b), __float_as_uint(a), 0x07060302u);
}

// ---------------- problem constants ----------------
// conv: [4,256,16,14,14] -> [4,512,16,14,14], 3x3x3 pad 1
// heads: K2 = 512*16 = 8192, M2 = 540+17280+36+72 = 17928, N2 = 4*196 = 784
#define OB1 423360      // out offset of bbox   (4*540*196)
#define OB2 13970880    // out offset of cls16  (OB1 + 4*17280*196)
#define OB3 13999104    // out offset of bbox16 (OB2 + 4*36*196)

// ws layout (bytes)
#define WS_XPAD   0
#define XPAD_GUARD_ELEMS 8192           /* 32 spatial slots * 256 ci */
#define WS_W1P    9519104               /* (32+18560)*256*2 */
#define WS_X2T    16596992              /* + 512*6912*2 */
#define WS_CLSS   31277056              /* + 896*8192*2 (X2T uses 832 rows of 896) */
#define WS_CLS16S 32970496              /* + 540*784*4 */
#define WS_BIAS2  33083392              /* + 36*784*4 */

// ---------------- small prep kernels ----------------
__global__ void k_zero(u32x4* __restrict__ p) {
  p[blockIdx.x * 256 + threadIdx.x] = (u32x4){0u, 0u, 0u, 0u};   // 2324*256 = XPAD/16B exactly
}

// base_feat [b][ci][t][y][x] (fp32) -> Xpad_T bf16 [guard + b*4608 + (t+1)*256 + (y+1)*16 + (x+1)][ci]
__global__ void k_fill_xpad(const float* __restrict__ bf, __hip_bfloat16* __restrict__ xp) {
  __shared__ float tile[64][65];
  int spb = blockIdx.x, cib = blockIdx.y, b = blockIdx.z;
  int t = threadIdx.x;
  int c0 = t >> 6;           // 0..3
  int sp_l = t & 63;
  const float* src = bf + (size_t)(b * 256 + cib * 64) * 3136 + spb * 64;
#pragma unroll
  for (int i = 0; i < 16; ++i) {
    int ci_l = i * 4 + c0;
    tile[ci_l][sp_l] = src[ci_l * 3136 + sp_l];   // tile[channel][spatial]
  }
  __syncthreads();
  int ci_l = t & 63;
#pragma unroll
  for (int i = 0; i < 16; ++i) {
    int spl = i * 4 + c0;
    int sp = spb * 64 + spl;
    int tt = sp / 196; int rr = sp - tt * 196;
    int y = rr / 14;   int x = rr - y * 14;
    int s = b * 4608 + (tt + 1) * 256 + (y + 1) * 16 + (x + 1);
    xp[(size_t)(32 + s) * 256 + cib * 64 + ci_l] = __float2bfloat16(tile[ci_l][spl]);
  }
}

// conv_w [co][ci][d] -> W1p bf16 [co][d*256+ci]
__global__ void k_pack_w1(const float* __restrict__ cw, __hip_bfloat16* __restrict__ w1p) {
  int i = blockIdx.x * 256 + threadIdx.x;      // 512*6912 exactly
  int co = i / 6912; int rem = i - co * 6912;
  int d = rem >> 8;  int ci = rem & 255;
  w1p[i] = __float2bfloat16(cw[co * 6912 + ci * 27 + d]);
}

__global__ void k_pack_bias2(const float* __restrict__ cb, const float* __restrict__ bb,
                             const float* __restrict__ c16, const float* __restrict__ b16,
                             float* __restrict__ bias2) {
  int i = blockIdx.x * 256 + threadIdx.x;
  if (i >= 18048) return;
  float v = 0.f;
  if (i < 540) v = cb[i];
  else if (i < 17820) v = bb[i - 540];
  else if (i < 17856) v = c16[i - 17820];
  else if (i < 17928) v = b16[i - 17856];
  bias2[i] = v;
}

// ---------------- GEMM1: conv as implicit GEMM ----------------
// R4: BM=64 x BN=256, BK=64, grid (64 ntile, 8 mtile) = 512 blocks = exactly 2/CU.
// Double-buffered GLL16 staging with counted vmcnt + raw s_barrier: the 10 loads
// for step i+1 stay in flight across step i's compute (no vmcnt(0) drain).
__global__ __launch_bounds__(256, 2) void k_gemm1(
    const __hip_bfloat16* __restrict__ W1p,
    const __hip_bfloat16* __restrict__ Xp,     // xpad + guard
    const float* __restrict__ conv_b,
    __hip_bfloat16* __restrict__ X2T) {
  __shared__ short lds[2][(64 + 256) * 64];    // per buf: lA[64][64] then lB[256][64]; 80 KB total
  const int tid = threadIdx.x;
  const int ntile = blockIdx.x, mtile = blockIdx.y;
  const int lane = tid & 63, wave = tid >> 6;
  const int wm = wave & 1, wn = wave >> 1;

  // affine staging bases: chunk i covers rows i*32 + (tid>>3); 32 % 8 == 0 keeps
  // the XOR-swizzle (pos ^ row&7) constant across chunks.
  const int srow = tid >> 3;
  const int kc8 = ((tid & 7) ^ (srow & 7)) * 8;
  const long gA0 = (long)(mtile * 64 + srow) * 6912 + kc8;
  const long gB0 = (long)((ntile >> 4) * 4608 + (ntile & 15) * 256 + srow) * 256 + kc8;

  f32x4 acc[2][8] = {};

  auto issue1 = [&](int it2, int buf2) {
    int d = it2 >> 2, ci0 = (it2 & 3) << 6;
    int dt = d / 9, r9 = d - dt * 9;
    int dy = r9 / 3, dx = r9 - dy * 3;
    long offA = d * 256 + ci0;
    long offB = (long)(dt * 256 + (dy - 1) * 16 + (dx - 1)) * 256 + ci0;
    short* la = &lds[buf2][0];
    short* lb = &lds[buf2][4096];
#pragma unroll
    for (int i = 0; i < 2; ++i)
      GLL16(W1p + gA0 + (long)i * 221184 + offA, &la[(i * 256 + tid) * 8]);
#pragma unroll
    for (int i = 0; i < 8; ++i)
      GLL16(Xp + gB0 + (long)i * 8192 + offB, &lb[(i * 256 + tid) * 8]);
  };

  issue1(0, 0);                       // prologue: step 0 into buf 0
#pragma unroll 1
  for (int it = 0; it < 108; ++it) {
    const int buf = it & 1;
    if (it + 1 < 108) {
      issue1(it + 1, buf ^ 1);        // 10 GLL16 for next step (stay in flight)
      asm volatile("s_waitcnt vmcnt(10)" ::: "memory");   // own step-it loads done
    } else {
      asm volatile("s_waitcnt vmcnt(0)" ::: "memory");
    }
    __builtin_amdgcn_s_barrier();     // all waves' step-it loads landed
    __builtin_amdgcn_sched_barrier(0);
    {
      const short* la = &lds[buf][0];
      const short* lb = &lds[buf][4096];
#pragma unroll
      for (int ks = 0; ks < 2; ++ks) {
        v8bf af[2];
#pragma unroll
        for (int mi = 0; mi < 2; ++mi) {
          int row = wm * 32 + mi * 16 + (lane & 15);
          int ch = (ks * 4 + (lane >> 4)) ^ (row & 7);
          af[mi] = *(const v8bf*)&la[row * 64 + ch * 8];
        }
#pragma unroll
        for (int ni = 0; ni < 8; ++ni) {
          int row = wn * 128 + ni * 16 + (lane & 15);
          int ch = (ks * 4 + (lane >> 4)) ^ (row & 7);
          v8bf bfr = *(const v8bf*)&lb[row * 64 + ch * 8];
          acc[0][ni] = __builtin_amdgcn_mfma_f32_16x16x32_bf16(af[0], bfr, acc[0][ni], 0, 0, 0);
          acc[1][ni] = __builtin_amdgcn_mfma_f32_16x16x32_bf16(af[1], bfr, acc[1][ni], 0, 0, 0);
        }
      }
    }
    __builtin_amdgcn_sched_barrier(0);
    __builtin_amdgcn_s_barrier();     // all waves done reading buf before it is reused
  }

  // epilogue: bias + relu, write bf16 to X2T[n2p][co*16+t], n2p = b*208 + y*14 + x
#pragma unroll
  for (int ni = 0; ni < 8; ++ni) {
    int col = ntile * 256 + wn * 128 + ni * 16 + (lane & 15);
    int bi = col >> 12, rem = col & 4095;
    int tt = rem >> 8, p2 = rem & 255;
    int yq = p2 >> 4, xq = p2 & 15;
    if (yq < 1 || yq > 14 || xq < 1 || xq > 14) continue;
    int n2p = bi * 208 + (yq - 1) * 14 + (xq - 1);
#pragma unroll
    for (int mi = 0; mi < 2; ++mi) {
#pragma unroll
      for (int rg = 0; rg < 4; ++rg) {
        int co = mtile * 64 + wm * 32 + mi * 16 + (lane >> 4) * 4 + rg;
        float v = acc[mi][ni][rg] + conv_b[co];
        v = fmaxf(v, 0.f);
        X2T[(size_t)n2p * 8192 + co * 16 + tt] = __float2bfloat16(v);
      }
    }
  }
}

// ---------------- GEMM2: heads ----------------
// R4: BM=128 x BN=208 (one batch per block), BK=64, 4 waves (wm=wave), 2 blocks/CU
// (72 KB LDS). Grid 576 (144 mtiles x 4 batches) with XCD-chunked swizzle so the
// 4 blocks sharing an A panel land on one XCD. Pipeline: B double-buffered via
// GLL16 one step ahead; A fp32 prefetched to regs TWO steps ahead; raw barriers
// with s_waitcnt vmcnt(23) keep next-B + both A prefetches in flight.
__global__ __launch_bounds__(256, 2) void k_gemm2(
    const float* __restrict__ cls_w, const float* __restrict__ bbox_w,
    const float* __restrict__ cls16_w, const float* __restrict__ bbox16_w,
    const __hip_bfloat16* __restrict__ X2T, const float* __restrict__ bias2,
    float* __restrict__ out, float* __restrict__ cls_s, float* __restrict__ cls16_s) {
  __shared__ short lA[128 * 64];       // 16 KB, single buffer (restaged each step)
  __shared__ short lB[2][224 * 64];    // 2 x 28 KB double buffer (224 rows staged, 208 used)
  const int tid = threadIdx.x;
  const int wsl = (int)(blockIdx.x & 7) * 72 + (int)(blockIdx.x >> 3);  // xcd-chunked
  const int mtile = wsl >> 2, ntile = wsl & 3;
  if (mtile >= 141) return;            // 144-pad tail (dummy blocks exit)
  const int lane = tid & 63, wm = tid >> 6;

  // A staging: thread t -> row r = t>>1 (0..127), half h = t&1 (32 floats each)
  const int r = tid >> 1, h = tid & 1;
  const float* rowptr;
  {
    int o = mtile * 128 + r;
    if (o >= 17928) o = 0;                      // pad rows -> finite dummy
    if (o < 540) rowptr = cls_w + (size_t)o * 8192;
    else if (o < 17820) rowptr = bbox_w + (size_t)(o - 540) * 8192;
    else if (o < 17856) rowptr = cls16_w + (size_t)(o - 17820) * 8192;
    else rowptr = bbox16_w + (size_t)(o - 17856) * 8192;
    rowptr += h * 32;
  }
  // B staging: affine base, chunk i -> rows i*32 + (tid>>3) (swizzle const in i)
  const long gB0 = (long)(ntile * 208 + (tid >> 3)) * 8192 +
                   (long)(((tid & 7) ^ ((tid >> 3) & 7)) * 8);

  f32x4 acc[2][13] = {};
  float4 vaA[8], vaB[8];

  auto loadA = [&](float4* va, int k0) {
    const float4* p = (const float4*)(rowptr + k0);
#pragma unroll
    for (int j = 0; j < 8; ++j) va[j] = p[j];
  };
  auto stageA = [&](const float4* va) {
#pragma unroll
    for (int j = 0; j < 4; ++j) {
      u32x4 wv;
      wv.x = pkbf(va[2 * j].x, va[2 * j].y);
      wv.y = pkbf(va[2 * j].z, va[2 * j].w);
      wv.z = pkbf(va[2 * j + 1].x, va[2 * j + 1].y);
      wv.w = pkbf(va[2 * j + 1].z, va[2 * j + 1].w);
      int pj = (h * 4 + j) ^ (r & 7);
      *(u32x4*)&lA[r * 64 + pj * 8] = wv;
    }
  };
  auto issueB = [&](int step, int bufb) {
    long off = (long)step * 64;
#pragma unroll
    for (int i = 0; i < 7; ++i)
      GLL16(X2T + gB0 + (long)i * 262144 + off, &lB[bufb][(i * 256 + tid) * 8]);
  };
  auto mfmaPhase = [&](int bufb) {
#pragma unroll
    for (int ks = 0; ks < 2; ++ks) {
      v8bf af0, af1;
      {
        int row0 = wm * 32 + (lane & 15);
        int ch0 = (ks * 4 + (lane >> 4)) ^ (row0 & 7);
        af0 = *(const v8bf*)&lA[row0 * 64 + ch0 * 8];
        af1 = *(const v8bf*)&lA[(row0 + 16) * 64 + ch0 * 8];   // +16 keeps row&7
      }
#pragma unroll
      for (int ni = 0; ni < 13; ++ni) {
        int row = ni * 16 + (lane & 15);
        int ch = (ks * 4 + (lane >> 4)) ^ (row & 7);
        v8bf bfr = *(const v8bf*)&lB[bufb][row * 64 + ch * 8];
        acc[0][ni] = __builtin_amdgcn_mfma_f32_16x16x32_bf16(af0, bfr, acc[0][ni], 0, 0, 0);
        acc[1][ni] = __builtin_amdgcn_mfma_f32_16x16x32_bf16(af1, bfr, acc[1][ni], 0, 0, 0);
      }
    }
  };

  // prologue: B0 in flight (oldest), then A for steps 0 and 1
  issueB(0, 0);
  loadA(vaA, 0);
  loadA(vaB, 64);

#pragma unroll 1
  for (int it = 0; it < 128; it += 2) {
    // ---- even half: compute step it on lB[0], stage vaA ----
    stageA(vaA);                      // compiler-counted wait drains vaA (and B(it) at it==0)
    issueB(it + 1, 1);                // B for step it+1
    if (it + 2 < 128) loadA(vaA, (it + 2) * 64);
    if (it < 126) asm volatile("s_waitcnt vmcnt(23) lgkmcnt(0)" ::: "memory"); // drain B(it)
    else          asm volatile("s_waitcnt vmcnt(15) lgkmcnt(0)" ::: "memory");
    __builtin_amdgcn_s_barrier();
    __builtin_amdgcn_sched_barrier(0);
    mfmaPhase(0);
    __builtin_amdgcn_sched_barrier(0);
    __builtin_amdgcn_s_barrier();
    // ---- odd half: compute step it+1 on lB[1], stage vaB ----
    stageA(vaB);
    if (it + 2 < 128) issueB(it + 2, 0);
    if (it + 3 < 128) loadA(vaB, (it + 3) * 64);
    if (it < 126) asm volatile("s_waitcnt vmcnt(23) lgkmcnt(0)" ::: "memory"); // drain B(it+1)
    else          asm volatile("s_waitcnt vmcnt(0) lgkmcnt(0)" ::: "memory");
    __builtin_amdgcn_s_barrier();
    __builtin_amdgcn_sched_barrier(0);
    mfmaPhase(1);
    __builtin_amdgcn_sched_barrier(0);
    __builtin_amdgcn_s_barrier();
  }

  // epilogue: + bias, route to out / score buffers (batch == ntile)
#pragma unroll
  for (int ni = 0; ni < 13; ++ni) {
    int cib = ni * 16 + (lane & 15);            // col within batch, 0..207
    if (cib >= 196) continue;
    int col = ntile * 196 + cib;                // 0..783 (cls_s/cls16_s column)
#pragma unroll
    for (int mi = 0; mi < 2; ++mi) {
#pragma unroll
      for (int rg = 0; rg < 4; ++rg) {
        int o = mtile * 128 + wm * 32 + mi * 16 + (lane >> 4) * 4 + rg;
        if (o >= 17928) continue;
        float val = acc[mi][ni][rg] + bias2[o];
        if (o < 540) cls_s[o * 784 + col] = val;
        else if (o < 17820) out[OB1 + ((size_t)ntile * 17280 + (o - 540)) * 196 + cib] = val;
        else if (o < 17856) cls16_s[(o - 17820) * 784 + col] = val;
        else out[OB3 + ((size_t)ntile * 72 + (o - 17856)) * 196 + cib] = val;
      }
    }
  }
}

// ---------------- pair softmax ----------------
__global__ void k_softmax_pairs(const float* __restrict__ s, float* __restrict__ out,
                                int half, int nc, long obase) {
  int idx = blockIdx.x * 256 + threadIdx.x;
  if (idx >= half * 784) return;
  int i = idx / 784, col = idx - i * 784;
  float s0 = s[i * 784 + col];
  float s1 = s[(i + half) * 784 + col];
  float m = fmaxf(s0, s1);
  float e0 = __expf(s0 - m), e1 = __expf(s1 - m);
  float inv = 1.0f / (e0 + e1);
  int bi = col / 196, yx = col - bi * 196;
  out[obase + ((size_t)bi * nc + i) * 196 + yx] = e0 * inv;
  out[obase + ((size_t)bi * nc + i + half) * 196 + yx] = e1 * inv;
}

// ---------------- launch ----------------
extern "C" void kernel_launch(void* const* d_in, const int* in_sizes, int n_in,
                              void* d_out, int out_size, void* d_ws, size_t ws_size,
                              hipStream_t stream) {
  const float* base_feat = (const float*)d_in[0];
  const float* conv_w = (const float*)d_in[4];
  const float* conv_b = (const float*)d_in[5];
  const float* cls_w = (const float*)d_in[6];
  const float* cls_b = (const float*)d_in[7];
  const float* bbox_w = (const float*)d_in[8];
  const float* bbox_b = (const float*)d_in[9];
  const float* cls16_w = (const float*)d_in[10];
  const float* cls16_b = (const float*)d_in[11];
  const float* bbox16_w = (const float*)d_in[12];
  const float* bbox16_b = (const float*)d_in[13];
  float* out = (float*)d_out;
  char* ws = (char*)d_ws;

  __hip_bfloat16* xpad = (__hip_bfloat16*)(ws + WS_XPAD);
  __hip_bfloat16* w1p = (__hip_bfloat16*)(ws + WS_W1P);
  __hip_bfloat16* x2t = (__hip_bfloat16*)(ws + WS_X2T);
  float* cls_s = (float*)(ws + WS_CLSS);
  float* cls16_s = (float*)(ws + WS_CLS16S);
  float* bias2 = (float*)(ws + WS_BIAS2);

  dim3 blk(256);
  k_zero<<<dim3(2324), blk, 0, stream>>>((u32x4*)(ws + WS_XPAD));
  k_fill_xpad<<<dim3(49, 4, 4), blk, 0, stream>>>(base_feat, xpad);
  k_pack_w1<<<dim3(13824), blk, 0, stream>>>(conv_w, w1p);
  k_pack_bias2<<<dim3(71), blk, 0, stream>>>(cls_b, bbox_b, cls16_b, bbox16_b, bias2);
  k_gemm1<<<dim3(64, 8), blk, 0, stream>>>(w1p, xpad + XPAD_GUARD_ELEMS, conv_b, x2t);
  k_gemm2<<<dim3(576), blk, 0, stream>>>(cls_w, bbox_w, cls16_w, bbox16_w, x2t, bias2,
                                         out, cls_s, cls16_s);
  k_softmax_pairs<<<dim3(827), blk, 0, stream>>>(cls_s, out, 270, 540, 0L);
  k_softmax_pairs<<<dim3(56), blk, 0, stream>>>(cls16_s, out, 18, 36, (long)OB2);
}

// Round 2
// 1367.889 us; speedup vs baseline: 1.0849x; 1.0355x over previous
//
#include <hip/hip_runtime.h>
#include <hip/hip_bf16.h>
#include <stdint.h>

// ---------------- types ----------------
typedef __attribute__((ext_vector_type(4))) float f32x4;
typedef __attribute__((ext_vector_type(4))) unsigned int u32x4;
typedef __bf16 v8bf __attribute__((ext_vector_type(8)));

// async global->LDS, 16B per lane. LDS dest must be uniform + lane*16.
#define GLL16(gp, lp) __builtin_amdgcn_global_load_lds( \
    (const __attribute__((address_space(1))) unsigned int*)(const void*)(gp), \
    (__attribute__((address_space(3))) unsigned int*)(void*)(lp), 16, 0, 0)

// pack two f32 -> two bf16 (truncate): short0=bf16(a) (lower k), short1=bf16(b)
__device__ __forceinline__ unsigned pkbf(float a, float b) {
  return __builtin_amdgcn_perm(__float_as_uint(b), __float_as_uint(a), 0x07060302u);
}

__device__ __forceinline__ v8bf cvt8(float4 f0, float4 f1) {
  u32x4 w;
  w.x = pkbf(f0.x, f0.y); w.y = pkbf(f0.z, f0.w);
  w.z = pkbf(f1.x, f1.y); w.w = pkbf(f1.z, f1.w);
  return *(v8bf*)&w;
}

// ---------------- problem constants ----------------
// conv: [4,256,16,14,14] -> [4,512,16,14,14], 3x3x3 pad 1
// heads: K2 = 512*16 = 8192, M2 = 540+17280+36+72 = 17928, N2 = 4*196 = 784
#define OB1 423360      // out offset of bbox   (4*540*196)
#define OB2 13970880    // out offset of cls16  (OB1 + 4*17280*196)
#define OB3 13999104    // out offset of bbox16 (OB2 + 4*36*196)

// ws layout (bytes)
#define WS_XPAD   0
#define XPAD_GUARD_ELEMS 8192           /* 32 spatial slots * 256 ci */
#define WS_W1P    9519104               /* (32+18560)*256*2 */
#define WS_X2T    16596992              /* + 512*6912*2 */
#define WS_CLSS   31277056              /* + 896*8192*2 (X2T uses 832 rows of 896) */
#define WS_CLS16S 32970496              /* + 540*784*4 */
#define WS_BIAS2  33083392              /* + 36*784*4 */

// ---------------- small prep kernels ----------------
__global__ void k_zero(u32x4* __restrict__ p) {
  p[blockIdx.x * 256 + threadIdx.x] = (u32x4){0u, 0u, 0u, 0u};   // 2324*256 = XPAD/16B exactly
}

// base_feat [b][ci][t][y][x] (fp32) -> Xpad_T bf16 [guard + b*4608 + (t+1)*256 + (y+1)*16 + (x+1)][ci]
__global__ void k_fill_xpad(const float* __restrict__ bf, __hip_bfloat16* __restrict__ xp) {
  __shared__ float tile[64][65];
  int spb = blockIdx.x, cib = blockIdx.y, b = blockIdx.z;
  int t = threadIdx.x;
  int c0 = t >> 6;           // 0..3
  int sp_l = t & 63;
  const float* src = bf + (size_t)(b * 256 + cib * 64) * 3136 + spb * 64;
#pragma unroll
  for (int i = 0; i < 16; ++i) {
    int ci_l = i * 4 + c0;
    tile[ci_l][sp_l] = src[ci_l * 3136 + sp_l];   // tile[channel][spatial]
  }
  __syncthreads();
  int ci_l = t & 63;
#pragma unroll
  for (int i = 0; i < 16; ++i) {
    int spl = i * 4 + c0;
    int sp = spb * 64 + spl;
    int tt = sp / 196; int rr = sp - tt * 196;
    int y = rr / 14;   int x = rr - y * 14;
    int s = b * 4608 + (tt + 1) * 256 + (y + 1) * 16 + (x + 1);
    xp[(size_t)(32 + s) * 256 + cib * 64 + ci_l] = __float2bfloat16(tile[ci_l][spl]);
  }
}

// conv_w [co][ci][d] -> W1p bf16 [co][d*256+ci]
__global__ void k_pack_w1(const float* __restrict__ cw, __hip_bfloat16* __restrict__ w1p) {
  int i = blockIdx.x * 256 + threadIdx.x;      // 512*6912 exactly
  int co = i / 6912; int rem = i - co * 6912;
  int d = rem >> 8;  int ci = rem & 255;
  w1p[i] = __float2bfloat16(cw[co * 6912 + ci * 27 + d]);
}

__global__ void k_pack_bias2(const float* __restrict__ cb, const float* __restrict__ bb,
                             const float* __restrict__ c16, const float* __restrict__ b16,
                             float* __restrict__ bias2) {
  int i = blockIdx.x * 256 + threadIdx.x;
  if (i >= 18048) return;
  float v = 0.f;
  if (i < 540) v = cb[i];
  else if (i < 17820) v = bb[i - 540];
  else if (i < 17856) v = c16[i - 17820];
  else if (i < 17928) v = b16[i - 17856];
  bias2[i] = v;
}

// ---------------- GEMM1: conv as implicit GEMM ----------------
// R5: BM=128 x BN=128, BK=64. Grid (128 ntile, 4 mtile) = 512 = exactly 2/CU,
// single round, no tail. Wave tile 64x64 (mi=4 x ni=4): 32 MFMA per 16 ds_reads
// (reuse 2.0). Double-buffered GLL16, counted vmcnt(8), raw barriers.
__global__ __launch_bounds__(256, 2) void k_gemm1(
    const __hip_bfloat16* __restrict__ W1p,
    const __hip_bfloat16* __restrict__ Xp,     // xpad + guard
    const float* __restrict__ conv_b,
    __hip_bfloat16* __restrict__ X2T) {
  __shared__ short lds[2][(128 + 128) * 64];   // per buf: lA[128][64] then lB[128][64]; 64 KB
  const int tid = threadIdx.x;
  const int ntile = blockIdx.x, mtile = blockIdx.y;
  const int lane = tid & 63, wave = tid >> 6;
  const int wm = wave & 1, wn = wave >> 1;

  // staging bases: chunk i covers rows i*32 + (tid>>3); 32 % 8 == 0 keeps the
  // XOR-swizzle (pos ^ row&7) constant across chunks.
  const int srow = tid >> 3;
  const int kc8 = ((tid & 7) ^ (srow & 7)) * 8;
  int gA[4], gB[4];
#pragma unroll
  for (int i = 0; i < 4; ++i) {
    gA[i] = (mtile * 128 + i * 32 + srow) * 6912 + kc8;
    int col = ntile * 128 + i * 32 + srow;
    int bi = col >> 12, rem = col & 4095;
    gB[i] = (bi * 4608 + rem) * 256 + kc8;
  }
  f32x4 acc[4][4] = {};

  auto issue1 = [&](int it2, int buf2) {
    int d = it2 >> 2, ci0 = (it2 & 3) << 6;
    int dt = d / 9, r9 = d - dt * 9;
    int dy = r9 / 3, dx = r9 - dy * 3;
    int offA = d * 256 + ci0;
    int offB = (dt * 256 + (dy - 1) * 16 + (dx - 1)) * 256 + ci0;
    short* la = &lds[buf2][0];
    short* lb = &lds[buf2][8192];
#pragma unroll
    for (int i = 0; i < 4; ++i)
      GLL16(W1p + gA[i] + offA, &la[(i * 256 + tid) * 8]);
#pragma unroll
    for (int i = 0; i < 4; ++i)
      GLL16(Xp + gB[i] + offB, &lb[(i * 256 + tid) * 8]);
  };

  issue1(0, 0);                       // prologue: step 0 into buf 0
#pragma unroll 1
  for (int it = 0; it < 108; ++it) {
    const int buf = it & 1;
    if (it + 1 < 108) {
      issue1(it + 1, buf ^ 1);        // 8 GLL16 for next step (stay in flight)
      asm volatile("s_waitcnt vmcnt(8)" ::: "memory");   // own step-it loads done
    } else {
      asm volatile("s_waitcnt vmcnt(0)" ::: "memory");
    }
    __builtin_amdgcn_s_barrier();     // all waves' step-it loads landed
    __builtin_amdgcn_sched_barrier(0);
    {
      const short* la = &lds[buf][0];
      const short* lb = &lds[buf][8192];
#pragma unroll
      for (int ks = 0; ks < 2; ++ks) {
        v8bf af[4], bfr[4];
#pragma unroll
        for (int mi = 0; mi < 4; ++mi) {
          int row = wm * 64 + mi * 16 + (lane & 15);
          int ch = (ks * 4 + (lane >> 4)) ^ (row & 7);
          af[mi] = *(const v8bf*)&la[row * 64 + ch * 8];
        }
#pragma unroll
        for (int ni = 0; ni < 4; ++ni) {
          int row = wn * 64 + ni * 16 + (lane & 15);
          int ch = (ks * 4 + (lane >> 4)) ^ (row & 7);
          bfr[ni] = *(const v8bf*)&lb[row * 64 + ch * 8];
        }
#pragma unroll
        for (int mi = 0; mi < 4; ++mi)
#pragma unroll
          for (int ni = 0; ni < 4; ++ni)
            acc[mi][ni] = __builtin_amdgcn_mfma_f32_16x16x32_bf16(af[mi], bfr[ni], acc[mi][ni], 0, 0, 0);
      }
    }
    __builtin_amdgcn_sched_barrier(0);
    __builtin_amdgcn_s_barrier();     // all waves done reading buf before reuse
  }

  // epilogue: bias + relu, write bf16 to X2T[n2p][co*16+t], n2p = b*208 + y*14 + x
#pragma unroll
  for (int ni = 0; ni < 4; ++ni) {
    int col = ntile * 128 + wn * 64 + ni * 16 + (lane & 15);
    int bi = col >> 12, rem = col & 4095;
    int tt = rem >> 8, p2 = rem & 255;
    int yq = p2 >> 4, xq = p2 & 15;
    if (yq < 1 || yq > 14 || xq < 1 || xq > 14) continue;
    int n2p = bi * 208 + (yq - 1) * 14 + (xq - 1);
#pragma unroll
    for (int mi = 0; mi < 4; ++mi) {
#pragma unroll
      for (int rg = 0; rg < 4; ++rg) {
        int co = mtile * 128 + wm * 64 + mi * 16 + (lane >> 4) * 4 + rg;
        float v = acc[mi][ni][rg] + conv_b[co];
        v = fmaxf(v, 0.f);
        X2T[(size_t)n2p * 8192 + co * 16 + tt] = __float2bfloat16(v);
      }
    }
  }
}

// ---------------- GEMM2: heads ----------------
// R5: BM=128 x BN=112 (784 = 7*112 exact, no pad cols), BK=64, 4 waves (pure
// M-split, 32 rows each). A loaded global->registers directly (per-lane
// fragment gather, line-coalesced) -> no lA, no ds_writes. LDS = B double
// buffer only (28 KB) -> 4 blocks/CU. Grid 1008 <= 1024 slots: single round.
// Swizzle co-locates all 7 readers of an A panel on one XCD (A L2-shared).
__global__ __launch_bounds__(256, 4) void k_gemm2(
    const float* __restrict__ cls_w, const float* __restrict__ bbox_w,
    const float* __restrict__ cls16_w, const float* __restrict__ bbox16_w,
    const __hip_bfloat16* __restrict__ X2T, const float* __restrict__ bias2,
    float* __restrict__ out, float* __restrict__ cls_s, float* __restrict__ cls16_s) {
  __shared__ short lB[2][112 * 64];    // 2 x 14 KB
  const int tid = threadIdx.x;
  // decode: x = XCD, same-mtile blocks share x -> co-resident on one XCD
  const int x = (int)blockIdx.x & 7;
  const int rest = (int)blockIdx.x >> 3;
  const int n = rest % 7, mgrp = rest / 7;
  const int mtile = mgrp * 8 + x;
  if (mtile >= 141) return;
  const int lane = tid & 63, wm = tid >> 6;

  // ---- A row pointers (per-lane; rows may span the 4 weight arrays) ----
  const float* rp0;
  const float* rp1;
  {
    int ob = mtile * 128 + wm * 32 + (lane & 15);
#pragma unroll
    for (int mi = 0; mi < 2; ++mi) {
      int o = ob + mi * 16;
      if (o >= 17928) o = 0;                    // pad rows -> finite dummy
      const float* p;
      if (o < 540) p = cls_w + (size_t)o * 8192;
      else if (o < 17820) p = bbox_w + (size_t)(o - 540) * 8192;
      else if (o < 17856) p = cls16_w + (size_t)(o - 17820) * 8192;
      else p = bbox16_w + (size_t)(o - 17856) * 8192;
      p += (lane >> 4) * 8;                     // k-chunk by lane quarter
      if (mi == 0) rp0 = p; else rp1 = p;
    }
  }

  // ---- B staging bases: 112 rows x 8 chunks = 896 slots = 3.5/thread ----
  int gB[4];
#pragma unroll
  for (int i = 0; i < 4; ++i) {
    int slot = i * 256 + tid;
    int row = slot >> 3, pos = slot & 7;
    if (row > 111) row = 111;                   // masked anyway
    int kc = pos ^ (row & 7);
    int rf = n * 112 + row;                     // flat col 0..783
    int bi = rf / 196, rr = rf - bi * 196;
    gB[i] = (bi * 208 + rr) * 8192 + kc * 8;
  }

  f32x4 acc[2][7] = {};
  float4 a4[8];

  auto issueB = [&](int step, int bufb) {
    int off = step * 64;
#pragma unroll
    for (int i = 0; i < 4; ++i) {
      if (i < 3 || tid < 128)                   // slots < 896 (wave-uniform mask)
        GLL16(X2T + gB[i] + off, &lB[bufb][(i * 256 + tid) * 8]);
    }
  };
  auto loadA = [&](int k0) {
    const float4* p0 = (const float4*)(rp0 + k0);
    const float4* p1 = (const float4*)(rp0 + k0 + 32);
    const float4* p2 = (const float4*)(rp1 + k0);
    const float4* p3 = (const float4*)(rp1 + k0 + 32);
    a4[0] = p0[0]; a4[1] = p0[1];   // mi0 ks0
    a4[2] = p1[0]; a4[3] = p1[1];   // mi0 ks1
    a4[4] = p2[0]; a4[5] = p2[1];   // mi1 ks0
    a4[6] = p3[0]; a4[7] = p3[1];   // mi1 ks1
  };

  // prologue
  issueB(0, 0);
  loadA(0);

#pragma unroll 1
  for (int it = 0; it < 128; ++it) {
    const int buf = it & 1;
    if (it < 127) issueB(it + 1, buf ^ 1);      // next-step B stays in flight
    // convert ks0 fragments; implicit vmcnt wait here drains B(it) (older)
    v8bf af00 = cvt8(a4[0], a4[1]);
    v8bf af10 = cvt8(a4[4], a4[5]);
    if (it < 127) asm volatile("s_waitcnt vmcnt(8)" ::: "memory");
    else          asm volatile("s_waitcnt vmcnt(0)" ::: "memory");
    __builtin_amdgcn_s_barrier();               // all waves' B(it) landed
    __builtin_amdgcn_sched_barrier(0);
    // ks0 MFMAs
#pragma unroll
    for (int ni = 0; ni < 7; ++ni) {
      int row = ni * 16 + (lane & 15);
      int ch = (lane >> 4) ^ (row & 7);
      v8bf bfr = *(const v8bf*)&lB[buf][row * 64 + ch * 8];
      acc[0][ni] = __builtin_amdgcn_mfma_f32_16x16x32_bf16(af00, bfr, acc[0][ni], 0, 0, 0);
      acc[1][ni] = __builtin_amdgcn_mfma_f32_16x16x32_bf16(af10, bfr, acc[1][ni], 0, 0, 0);
    }
    // convert ks1 fragments (a4[2,3,6,7] retired long ago), then refill a4
    v8bf af01 = cvt8(a4[2], a4[3]);
    v8bf af11 = cvt8(a4[6], a4[7]);
    if (it < 127) loadA((it + 1) * 64);         // next-step A, lands by next top
    // ks1 MFMAs
#pragma unroll
    for (int ni = 0; ni < 7; ++ni) {
      int row = ni * 16 + (lane & 15);
      int ch = (4 + (lane >> 4)) ^ (row & 7);
      v8bf bfr = *(const v8bf*)&lB[buf][row * 64 + ch * 8];
      acc[0][ni] = __builtin_amdgcn_mfma_f32_16x16x32_bf16(af01, bfr, acc[0][ni], 0, 0, 0);
      acc[1][ni] = __builtin_amdgcn_mfma_f32_16x16x32_bf16(af11, bfr, acc[1][ni], 0, 0, 0);
    }
    __builtin_amdgcn_sched_barrier(0);
    __builtin_amdgcn_s_barrier();               // all waves done reading buf
  }

  // epilogue: + bias, route to out / score buffers
#pragma unroll
  for (int ni = 0; ni < 7; ++ni) {
    int colf = n * 112 + ni * 16 + (lane & 15); // 0..783, all valid
    int bi = colf / 196, cib = colf - bi * 196;
#pragma unroll
    for (int mi = 0; mi < 2; ++mi) {
#pragma unroll
      for (int rg = 0; rg < 4; ++rg) {
        int o = mtile * 128 + wm * 32 + mi * 16 + (lane >> 4) * 4 + rg;
        if (o >= 17928) continue;
        float val = acc[mi][ni][rg] + bias2[o];
        if (o < 540) cls_s[o * 784 + colf] = val;
        else if (o < 17820) out[OB1 + ((size_t)bi * 17280 + (o - 540)) * 196 + cib] = val;
        else if (o < 17856) cls16_s[(o - 17820) * 784 + colf] = val;
        else out[OB3 + ((size_t)bi * 72 + (o - 17856)) * 196 + cib] = val;
      }
    }
  }
}

// ---------------- pair softmax ----------------
__global__ void k_softmax_pairs(const float* __restrict__ s, float* __restrict__ out,
                                int half, int nc, long obase) {
  int idx = blockIdx.x * 256 + threadIdx.x;
  if (idx >= half * 784) return;
  int i = idx / 784, col = idx - i * 784;
  float s0 = s[i * 784 + col];
  float s1 = s[(i + half) * 784 + col];
  float m = fmaxf(s0, s1);
  float e0 = __expf(s0 - m), e1 = __expf(s1 - m);
  float inv = 1.0f / (e0 + e1);
  int bi = col / 196, yx = col - bi * 196;
  out[obase + ((size_t)bi * nc + i) * 196 + yx] = e0 * inv;
  out[obase + ((size_t)bi * nc + i + half) * 196 + yx] = e1 * inv;
}

// ---------------- launch ----------------
extern "C" void kernel_launch(void* const* d_in, const int* in_sizes, int n_in,
                              void* d_out, int out_size, void* d_ws, size_t ws_size,
                              hipStream_t stream) {
  const float* base_feat = (const float*)d_in[0];
  const float* conv_w = (const float*)d_in[4];
  const float* conv_b = (const float*)d_in[5];
  const float* cls_w = (const float*)d_in[6];
  const float* cls_b = (const float*)d_in[7];
  const float* bbox_w = (const float*)d_in[8];
  const float* bbox_b = (const float*)d_in[9];
  const float* cls16_w = (const float*)d_in[10];
  const float* cls16_b = (const float*)d_in[11];
  const float* bbox16_w = (const float*)d_in[12];
  const float* bbox16_b = (const float*)d_in[13];
  float* out = (float*)d_out;
  char* ws = (char*)d_ws;

  __hip_bfloat16* xpad = (__hip_bfloat16*)(ws + WS_XPAD);
  __hip_bfloat16* w1p = (__hip_bfloat16*)(ws + WS_W1P);
  __hip_bfloat16* x2t = (__hip_bfloat16*)(ws + WS_X2T);
  float* cls_s = (float*)(ws + WS_CLSS);
  float* cls16_s = (float*)(ws + WS_CLS16S);
  float* bias2 = (float*)(ws + WS_BIAS2);

  dim3 blk(256);
  k_zero<<<dim3(2324), blk, 0, stream>>>((u32x4*)(ws + WS_XPAD));
  k_fill_xpad<<<dim3(49, 4, 4), blk, 0, stream>>>(base_feat, xpad);
  k_pack_w1<<<dim3(13824), blk, 0, stream>>>(conv_w, w1p);
  k_pack_bias2<<<dim3(71), blk, 0, stream>>>(cls_b, bbox_b, cls16_b, bbox16_b, bias2);
  k_gemm1<<<dim3(128, 4), blk, 0, stream>>>(w1p, xpad + XPAD_GUARD_ELEMS, conv_b, x2t);
  k_gemm2<<<dim3(1008), blk, 0, stream>>>(cls_w, bbox_w, cls16_w, bbox16_w, x2t, bias2,
                                          out, cls_s, cls16_s);
  k_softmax_pairs<<<dim3(827), blk, 0, stream>>>(cls_s, out, 270, 540, 0L);
  k_softmax_pairs<<<dim3(56), blk, 0, stream>>>(cls16_s, out, 18, 36, (long)OB2);
}